// Round 11
// baseline (351.520 us; speedup 1.0000x reference)
//
#include <hip/hip_runtime.h>
#include <math.h>

#define NB 2
#define NL 256
#define DM 512
#define NH 8
#define DQ 64
#define NBLK 512

// ---------------------------------------------------------------------------
// DPP whole-wave rotate by 2 lanes (pure VALU) — R6-verified direction codes.
// ---------------------------------------------------------------------------
__device__ __forceinline__ float rot_up2(float x) {   // lane i <- lane (i+2)%64
    int v = __builtin_amdgcn_mov_dpp(__float_as_int(x), 0x134, 0xF, 0xF, true);
    v = __builtin_amdgcn_mov_dpp(v, 0x134, 0xF, 0xF, true);
    return __int_as_float(v);
}
__device__ __forceinline__ float rot_dn2(float x) {   // lane i <- lane (i-2)%64
    int v = __builtin_amdgcn_mov_dpp(__float_as_int(x), 0x13C, 0xF, 0xF, true);
    v = __builtin_amdgcn_mov_dpp(v, 0x13C, 0xF, 0xF, true);
    return __int_as_float(v);
}

// ---------------------------------------------------------------------------
// Grid barrier: all NBLK blocks are co-resident by construction
// (launch_bounds(256,2): VGPR<=256 cap, LDS 17.4KB -> 2 blocks/CU x 256 CU
//  = 512 slots = grid). Release: syncthreads drains block stores to L2,
// threadfence does agent-scope L2 writeback; acquire: threadfence after the
// spin invalidates L1/L2 (per-CU L1 is shared by the whole block).
// ---------------------------------------------------------------------------
__device__ __forceinline__ void grid_bar(unsigned* c, unsigned n) {
    __syncthreads();
    if (threadIdx.x == 0) {
        __threadfence();
        atomicAdd(c, 1u);
        while (__hip_atomic_load(c, __ATOMIC_RELAXED, __HIP_MEMORY_SCOPE_AGENT) < n)
            __builtin_amdgcn_s_sleep(2);
        __threadfence();
    }
    __syncthreads();
}

// ---------------------------------------------------------------------------
// Fused pipeline: qkv GEMM -> attn softmax + u -> EUNN rnn -> out GEMM.
// All phase bodies are verbatim from previously-PASSED kernels
// (P1: R3 32x64 qkv + R9 kT store; P2: R9/R10 attn_u; P3: R6 rnn — the
// measured-best 2-elem/lane DPP scheme at 2 waves/SIMD; P4: R8 out 32x64).
// ---------------------------------------------------------------------------
__global__ __launch_bounds__(256, 2) void fused_kernel(
    const float* __restrict__ xq, const float* __restrict__ xk,
    const float* __restrict__ xv, const float* __restrict__ mask,
    const float* __restrict__ Wq, const float* __restrict__ bq_,
    const float* __restrict__ Wk, const float* __restrict__ bk_,
    const float* __restrict__ Wv, const float* __restrict__ bv_,
    const float* __restrict__ Wo, const float* __restrict__ bo_,
    const float* __restrict__ theta, const float* __restrict__ phi,
    const float* __restrict__ Wre, const float* __restrict__ Wim,
    const float* __restrict__ rb,
    float* qbuf, float* kTbuf, float* vbuf, float2* ubuf,
    float* rnnbuf, float* outbuf, float* attnbuf, unsigned* bars)
{
    __shared__ __align__(16) char smem_pool[17408];
    int tid = threadIdx.x;

    // ================= phase 1: QKV projection (384 jobs, 32x64 tiles) ====
    {
        int job = blockIdx.x;
        if (job < 384) {
            float (*As)[33] = (float (*)[33])smem_pool;            // 4224 B
            float (*Bs)[68] = (float (*)[68])(smem_pool + 4224);   // 8704 B
            int z = job / 128, r1 = job % 128;
            int mt = r1 >> 3, nt = r1 & 7;
            const float* X = (z == 0) ? xq : (z == 1) ? xk : xv;
            const float* W = (z == 0) ? Wq : (z == 1) ? Wk : Wv;
            const float* bias = (z == 0) ? bq_ : (z == 1) ? bk_ : bv_;
            float* O = (z == 0) ? qbuf : (z == 1) ? kTbuf : vbuf;
            int tx = tid & 15, ty = tid >> 4;
            int m0 = mt * 32, n0 = nt * 64;
            float acc[2][4] = {};
            for (int k0 = 0; k0 < 512; k0 += 32) {
                {
                    int r = tid >> 3, c4 = (tid & 7) * 4;
                    float4 av = *(const float4*)(X + (m0 + r) * 512 + k0 + c4);
                    As[c4 + 0][r] = av.x; As[c4 + 1][r] = av.y;
                    As[c4 + 2][r] = av.z; As[c4 + 3][r] = av.w;
                }
                {
                    int r = tid >> 4, c4 = (tid & 15) * 4;
                    float4 b0 = *(const float4*)(W + (k0 + r) * 512 + n0 + c4);
                    float4 b1 = *(const float4*)(W + (k0 + r + 16) * 512 + n0 + c4);
                    *(float4*)&Bs[r][c4] = b0;
                    *(float4*)&Bs[r + 16][c4] = b1;
                }
                __syncthreads();
                #pragma unroll
                for (int kk = 0; kk < 32; kk++) {
                    float a0 = As[kk][ty * 2 + 0], a1 = As[kk][ty * 2 + 1];
                    float4 bb = *(const float4*)&Bs[kk][tx * 4];
                    acc[0][0] += a0 * bb.x; acc[0][1] += a0 * bb.y;
                    acc[0][2] += a0 * bb.z; acc[0][3] += a0 * bb.w;
                    acc[1][0] += a1 * bb.x; acc[1][1] += a1 * bb.y;
                    acc[1][2] += a1 * bb.z; acc[1][3] += a1 * bb.w;
                }
                __syncthreads();
            }
            #pragma unroll
            for (int i = 0; i < 2; i++) {
                int m = m0 + ty * 2 + i;
                int bb_ = m >> 8, l = m & 255;
                #pragma unroll
                for (int jj = 0; jj < 4; jj++) {
                    int n = n0 + tx * 4 + jj;
                    int hh = n >> 6, dd = n & 63;
                    float val = acc[i][jj] + bias[n];
                    if (z == 1) O[((bb_ * NH + hh) * DQ + dd) * NL + l] = val; // kT
                    else        O[((bb_ * NH + hh) * NL + l) * DQ + dd] = val;
                }
            }
        }
    }
    grid_bar(&bars[0], NBLK);

    // ================= phase 2: attn softmax + u (5120 jobs) ==============
    {
        float* sp = (float*)smem_pool;
        for (int j = blockIdx.x; j < 5120; j += NBLK) {
            int x = j % 320;
            int hb = j / 320;
            int h = hb & 7, b = hb >> 3;
            if (x < 256) {
                int qi = x;
                int wv = tid >> 6, lane = tid & 63;
                float* qrow = sp; float* wred = sp + 256; float* wsum = sp + 260;
                if (tid < 16)
                    ((float4*)qrow)[tid] =
                        ((const float4*)(qbuf + ((b * NH + h) * NL + qi) * DQ))[tid];
                __syncthreads();
                const float* kp = kTbuf + (size_t)((b * NH + h) * DQ) * NL + tid;
                float acc = 0.f;
                #pragma unroll
                for (int d = 0; d < 64; d++) acc += qrow[d] * kp[d * NL];
                acc *= 0.125f;
                float mv = mask[(b * NL + qi) * NL + tid];
                acc -= (mv == 1.0f) ? INFINITY : mv;
                float mx = acc;
                #pragma unroll
                for (int o = 32; o; o >>= 1) mx = fmaxf(mx, __shfl_xor(mx, o, 64));
                if (lane == 0) wred[wv] = mx;
                __syncthreads();
                mx = fmaxf(fmaxf(wred[0], wred[1]), fmaxf(wred[2], wred[3]));
                float e = __expf(acc - mx);
                float s = e;
                #pragma unroll
                for (int o = 32; o; o >>= 1) s += __shfl_xor(s, o, 64);
                if (lane == 0) wsum[wv] = s;
                __syncthreads();
                s = wsum[0] + wsum[1] + wsum[2] + wsum[3];
                attnbuf[((b * NH + h) * NL + qi) * NL + tid] =
                    e * __builtin_amdgcn_rcpf(s);
            } else {
                int xi = x - 256;
                int e = tid & 63, tq = tid >> 6;
                int t = xi * 4 + tq;
                float (*vrow)[64] = (float (*)[64])sp;
                vrow[tq][e] = vbuf[((b * NH + h) * NL + t) * DQ + e];
                __syncthreads();
                const float* wr = Wre + h * 4096 + e;
                const float* wi = Wim + h * 4096 + e;
                float ar = 0.f, ai = 0.f;
                #pragma unroll
                for (int d = 0; d < 64; d++) {
                    float vv = vrow[tq][d];
                    ar += vv * wr[d * 64];
                    ai += vv * wi[d * 64];
                }
                ubuf[((b * NH + h) * NL + t) * DQ + e] = make_float2(ar, ai);
            }
            __syncthreads();
        }
    }
    grid_bar(&bars[1], NBLK);

    // ================= phase 3: EUNN recurrence (R6 scheme, 8 recs/block) ==
    {
        int wv = tid >> 6;
        int lane = tid & 63;
        int par = lane & 1;
        int p = lane >> 1;
        int rec = blockIdx.x * 8 + wv * 2 + par;     // 0..4095
        int qi = rec & 255, h = (rec >> 8) & 7, b = rec >> 11;

        const float* tb = theta + h * 64;
        const float* pb = phi + h * 64;

        float th0 = tb[p], ph0 = pb[p];
        float c0 = cosf(th0), s0 = sinf(th0);
        float cp0 = cosf(ph0), sp0 = sinf(ph0);
        float W0ar = -s0 * cp0, W0ai = -s0 * sp0;
        float W0br =  s0 * cp0, W0bi = -s0 * sp0;

        float th1 = tb[32 + p], ph1 = pb[32 + p];
        float c1 = cosf(th1), s1v = sinf(th1);
        float W1ar = -s1v * cosf(ph1), W1ai = -s1v * sinf(ph1);

        int pm = (p + 31) & 31;
        float th1m = tb[32 + pm], ph1m = pb[32 + pm];
        float c1m = cosf(th1m), s1m = sinf(th1m);
        float W1br = s1m * cosf(ph1m), W1bi = -s1m * sinf(ph1m);

        float bias0 = rb[h * 64 + 2 * p];
        float bias1 = rb[h * 64 + 2 * p + 1];

        float* arow = (float*)smem_pool;             // 8 rows x stride 257
        const float* ap = attnbuf + (size_t)blockIdx.x * 2048;
        #pragma unroll
        for (int i = 0; i < 8; i++) arow[i * 257 + tid] = ap[i * 256 + tid];
        __syncthreads();
        const float* arc = arow + (wv * 2 + par) * 257;

        const float4* up4 =
            (const float4*)(ubuf + (size_t)((b * NH + h) * NL) * DQ) + p;

        float e0r = 0.f, e0i = 0.f, e1r = 0.f, e1i = 0.f;
        #pragma unroll 8
        for (int t = 0; t < 256; t++) {
            float4 uu = up4[t * 32];
            float a_t = arc[t];

            float na_r = c0 * e0r + (W0ar * e1r - W0ai * e1i);
            float na_i = c0 * e0i + (W0ar * e1i + W0ai * e1r);
            float nb_r = c0 * e1r + (W0br * e0r - W0bi * e0i);
            float nb_i = c0 * e1i + (W0br * e0i + W0bi * e0r);

            float f1r = rot_up2(na_r), f1i = rot_up2(na_i);
            float f2r = rot_dn2(nb_r), f2i = rot_dn2(nb_i);

            float z1r = c1 * nb_r + (W1ar * f1r - W1ai * f1i) + a_t * uu.z;
            float z1i = c1 * nb_i + (W1ar * f1i + W1ai * f1r) + a_t * uu.w;
            float z0r = c1m * na_r + (W1br * f2r - W1bi * f2i) + a_t * uu.x;
            float z0i = c1m * na_i + (W1br * f2i + W1bi * f2r) + a_t * uu.y;

            // modrelu — exact reference form (R7 lesson: no rsqrt fold)
            float mm0 = z0r * z0r + z0i * z0i;
            float m0v = __builtin_amdgcn_sqrtf(mm0);
            float sc0 = fmaxf(m0v + bias0, 0.f) * __builtin_amdgcn_rcpf(m0v + 1e-5f);
            e0r = z0r * sc0; e0i = z0i * sc0;

            float mm1 = z1r * z1r + z1i * z1i;
            float m1v = __builtin_amdgcn_sqrtf(mm1);
            float sc1 = fmaxf(m1v + bias1, 0.f) * __builtin_amdgcn_rcpf(m1v + 1e-5f);
            e1r = z1r * sc1; e1i = z1i * sc1;
        }

        *(float2*)&rnnbuf[(size_t)(b * NL + qi) * DM + h * DQ + 2 * p] =
            make_float2(e0r, e1r);
    }
    grid_bar(&bars[2], NBLK);

    // ================= phase 4: output projection (128 jobs, 32x64) =======
    {
        int job = blockIdx.x;
        if (job < 128) {
            float (*As)[33] = (float (*)[33])smem_pool;
            float (*Bs)[68] = (float (*)[68])(smem_pool + 4224);
            int mt = job >> 3, nt = job & 7;
            int tx = tid & 15, ty = tid >> 4;
            int m0 = mt * 32, n0 = nt * 64;
            float acc[2][4] = {};
            for (int k0 = 0; k0 < 512; k0 += 32) {
                {
                    int r = tid >> 3, c4 = (tid & 7) * 4;
                    float4 av = *(const float4*)(rnnbuf + (m0 + r) * 512 + k0 + c4);
                    As[c4 + 0][r] = av.x; As[c4 + 1][r] = av.y;
                    As[c4 + 2][r] = av.z; As[c4 + 3][r] = av.w;
                }
                {
                    int r = tid >> 4, c4 = (tid & 15) * 4;
                    float4 b0 = *(const float4*)(Wo + (k0 + r) * 512 + n0 + c4);
                    float4 b1 = *(const float4*)(Wo + (k0 + r + 16) * 512 + n0 + c4);
                    *(float4*)&Bs[r][c4] = b0;
                    *(float4*)&Bs[r + 16][c4] = b1;
                }
                __syncthreads();
                #pragma unroll
                for (int kk = 0; kk < 32; kk++) {
                    float a0 = As[kk][ty * 2 + 0], a1 = As[kk][ty * 2 + 1];
                    float4 bb = *(const float4*)&Bs[kk][tx * 4];
                    acc[0][0] += a0 * bb.x; acc[0][1] += a0 * bb.y;
                    acc[0][2] += a0 * bb.z; acc[0][3] += a0 * bb.w;
                    acc[1][0] += a1 * bb.x; acc[1][1] += a1 * bb.y;
                    acc[1][2] += a1 * bb.z; acc[1][3] += a1 * bb.w;
                }
                __syncthreads();
            }
            #pragma unroll
            for (int i = 0; i < 2; i++) {
                int m = m0 + ty * 2 + i;
                #pragma unroll
                for (int jj = 0; jj < 4; jj++) {
                    int n = n0 + tx * 4 + jj;
                    outbuf[m * 512 + n] = acc[i][jj] + bo_[n];
                }
            }
        }
    }
}

// ---------------------------------------------------------------------------
extern "C" void kernel_launch(void* const* d_in, const int* in_sizes, int n_in,
                              void* d_out, int out_size, void* d_ws, size_t ws_size,
                              hipStream_t stream)
{
    const float* x_q  = (const float*)d_in[0];
    const float* x_k  = (const float*)d_in[1];
    const float* x_v  = (const float*)d_in[2];
    const float* mask = (const float*)d_in[3];
    const float* Wq   = (const float*)d_in[4];
    const float* bq   = (const float*)d_in[5];
    const float* Wk   = (const float*)d_in[6];
    const float* bk   = (const float*)d_in[7];
    const float* Wv   = (const float*)d_in[8];
    const float* bv   = (const float*)d_in[9];
    const float* Wo   = (const float*)d_in[10];
    const float* bo   = (const float*)d_in[11];
    const float* theta= (const float*)d_in[12];
    const float* phi  = (const float*)d_in[13];
    const float* Wre  = (const float*)d_in[14];
    const float* Wim  = (const float*)d_in[15];
    const float* rb   = (const float*)d_in[16];

    float* ws = (float*)d_ws;
    float*    q_ws  = ws;                        // 262144 f
    float*    kT_ws = ws + 262144;               // 262144 f (b,h,d,t)
    float*    v_ws  = ws + 524288;               // 262144 f
    float2*   u_ws  = (float2*)(ws + 786432);    // 262144 float2
    float*    rnn_o = ws + 1310720;              // 262144 f
    unsigned* bars  = (unsigned*)(ws + 1572864); // 3 barrier counters

    float* out_o  = (float*)d_out;               // (2,256,512)
    float* attn_o = out_o + NB * NL * DM;        // (2,8,256,256)

    hipMemsetAsync(bars, 0, 3 * sizeof(unsigned), stream);

    fused_kernel<<<dim3(NBLK), 256, 0, stream>>>(
        x_q, x_k, x_v, mask, Wq, bq, Wk, bk, Wv, bv, Wo, bo,
        theta, phi, Wre, Wim, rb,
        q_ws, kT_ws, v_ws, u_ws, rnn_o, out_o, attn_o, bars);
}

// Round 12
// 195.766 us; speedup vs baseline: 1.7956x; 1.7956x over previous
//
#include <hip/hip_runtime.h>
#include <math.h>

#define NB 2
#define NL 256
#define DM 512
#define NH 8
#define DQ 64

// ---------------------------------------------------------------------------
// K1: QKV projection GEMM. 32x64 tile, K-tile 32, thread tile 2x4 (R3 config,
// measured-best). k (z==1) written TRANSPOSED (b,h,d,t). grid (8,16,3).
// ---------------------------------------------------------------------------
__global__ __launch_bounds__(256) void qkv_gemm(
    const float* __restrict__ xq, const float* __restrict__ xk,
    const float* __restrict__ xv,
    const float* __restrict__ Wq, const float* __restrict__ Wk,
    const float* __restrict__ Wv,
    const float* __restrict__ bq, const float* __restrict__ bk,
    const float* __restrict__ bv,
    float* __restrict__ q, float* __restrict__ k, float* __restrict__ v)
{
    int z = blockIdx.z;
    const float* X = (z == 0) ? xq : (z == 1) ? xk : xv;
    const float* W = (z == 0) ? Wq : (z == 1) ? Wk : Wv;
    const float* bias = (z == 0) ? bq : (z == 1) ? bk : bv;
    float* O = (z == 0) ? q : (z == 1) ? k : v;

    __shared__ float As[32][33];
    __shared__ float Bs[32][68];

    int tid = threadIdx.x;
    int tx = tid & 15, ty = tid >> 4;
    int m0 = blockIdx.y * 32, n0 = blockIdx.x * 64;

    float acc[2][4] = {};

    for (int k0 = 0; k0 < 512; k0 += 32) {
        {
            int r = tid >> 3, c4 = (tid & 7) * 4;
            const float4 av = *(const float4*)(X + (m0 + r) * 512 + k0 + c4);
            As[c4 + 0][r] = av.x; As[c4 + 1][r] = av.y;
            As[c4 + 2][r] = av.z; As[c4 + 3][r] = av.w;
        }
        {
            int r = tid >> 4, c4 = (tid & 15) * 4;
            float4 b0 = *(const float4*)(W + (k0 + r) * 512 + n0 + c4);
            float4 b1 = *(const float4*)(W + (k0 + r + 16) * 512 + n0 + c4);
            *(float4*)&Bs[r][c4] = b0;
            *(float4*)&Bs[r + 16][c4] = b1;
        }
        __syncthreads();
        #pragma unroll
        for (int kk = 0; kk < 32; kk++) {
            float a0 = As[kk][ty * 2 + 0];
            float a1 = As[kk][ty * 2 + 1];
            float4 bb = *(const float4*)&Bs[kk][tx * 4];
            acc[0][0] += a0 * bb.x; acc[0][1] += a0 * bb.y;
            acc[0][2] += a0 * bb.z; acc[0][3] += a0 * bb.w;
            acc[1][0] += a1 * bb.x; acc[1][1] += a1 * bb.y;
            acc[1][2] += a1 * bb.z; acc[1][3] += a1 * bb.w;
        }
        __syncthreads();
    }

    #pragma unroll
    for (int i = 0; i < 2; i++) {
        int m = m0 + ty * 2 + i;
        int b = m >> 8, l = m & 255;
        #pragma unroll
        for (int j = 0; j < 4; j++) {
            int n = n0 + tx * 4 + j;
            int h = n >> 6, d = n & 63;
            float val = acc[i][j] + bias[n];
            if (z == 1)
                O[((b * NH + h) * DQ + d) * NL + l] = val;   // kT: (b,h,d,t)
            else
                O[((b * NH + h) * NL + l) * DQ + d] = val;
        }
    }
}

// ---------------------------------------------------------------------------
// K2: fused attn softmax (8 q-rows per block, tiled) + u precompute.
// grid.x: 0..31 = attn group (8 q rows), 32..95 = u jobs.
// attn: thread t holds logits for its key across 8 q rows in registers;
// kT read coalesced ONCE per block (8x reuse vs per-row blocks).
// ---------------------------------------------------------------------------
__global__ __launch_bounds__(256) void attn_u_kernel(
    const float* __restrict__ q, const float* __restrict__ kT,
    const float* __restrict__ mask, float* __restrict__ attn_o,
    const float* __restrict__ v, const float* __restrict__ Wre,
    const float* __restrict__ Wim, float2* __restrict__ u)
{
    int h = blockIdx.y, b = blockIdx.z;
    int tid = threadIdx.x;
    int x = blockIdx.x;
    __shared__ float sp[2608];   // qs[512] | lg[8*260] | redm[8] | reds[8]

    if (x < 32) {
        int qg = x;
        int wv = tid >> 6, lane = tid & 63;
        float* qs   = sp;
        float* lg   = sp + 512;
        float* redm = sp + 512 + 2080;
        float* reds = redm + 8;

        // 8 q rows (contiguous in (b,h,l,d)) -> LDS
        ((float2*)qs)[tid] =
            ((const float2*)(q + ((size_t)(b * NH + h) * NL + qg * 8) * DQ))[tid];
        __syncthreads();

        const float* kp = kT + (size_t)((b * NH + h) * DQ) * NL + tid;
        float acc[8] = {};
        #pragma unroll
        for (int d4 = 0; d4 < 16; d4++) {
            float kv0 = kp[(d4 * 4 + 0) * NL];
            float kv1 = kp[(d4 * 4 + 1) * NL];
            float kv2 = kp[(d4 * 4 + 2) * NL];
            float kv3 = kp[(d4 * 4 + 3) * NL];
            #pragma unroll
            for (int j = 0; j < 8; j++) {
                const float4 qv = *(const float4*)&qs[j * 64 + d4 * 4];
                acc[j] += qv.x * kv0 + qv.y * kv1 + qv.z * kv2 + qv.w * kv3;
            }
        }
        #pragma unroll
        for (int j = 0; j < 8; j++) {
            float mv = mask[(size_t)(b * NL + qg * 8 + j) * NL + tid];
            acc[j] = acc[j] * 0.125f - ((mv == 1.0f) ? INFINITY : mv);
            lg[j * 260 + tid] = acc[j];
        }
        __syncthreads();
        // wave wv reduces rows 2wv, 2wv+1
        #pragma unroll
        for (int jj = 0; jj < 2; jj++) {
            int j = wv * 2 + jj;
            float v0 = lg[j * 260 + lane],       v1 = lg[j * 260 + 64 + lane];
            float v2 = lg[j * 260 + 128 + lane], v3 = lg[j * 260 + 192 + lane];
            float mx = fmaxf(fmaxf(v0, v1), fmaxf(v2, v3));
            #pragma unroll
            for (int o = 32; o; o >>= 1) mx = fmaxf(mx, __shfl_xor(mx, o, 64));
            float s = __expf(v0 - mx) + __expf(v1 - mx) +
                      __expf(v2 - mx) + __expf(v3 - mx);
            #pragma unroll
            for (int o = 32; o; o >>= 1) s += __shfl_xor(s, o, 64);
            if (lane == 0) { redm[j] = mx; reds[j] = s; }
        }
        __syncthreads();
        #pragma unroll
        for (int j = 0; j < 8; j++) {
            float p = __expf(acc[j] - redm[j]) * __builtin_amdgcn_rcpf(reds[j]);
            attn_o[((size_t)(b * NH + h) * NL + qg * 8 + j) * NL + tid] = p;
        }
    } else {
        int xi = x - 32;                    // 0..63
        int e = tid & 63, tq = tid >> 6;
        int t = xi * 4 + tq;
        float (*vrow)[64] = (float (*)[64])sp;

        vrow[tq][e] = v[((b * NH + h) * NL + t) * DQ + e];
        __syncthreads();

        const float* wr = Wre + h * 4096 + e;
        const float* wi = Wim + h * 4096 + e;
        float ar = 0.f, ai = 0.f;
        #pragma unroll
        for (int d = 0; d < 64; d++) {
            float vv = vrow[tq][d];
            ar += vv * wr[d * 64];
            ai += vv * wi[d * 64];
        }
        u[((b * NH + h) * NL + t) * DQ + e] = make_float2(ar, ai);
    }
}

// ---------------------------------------------------------------------------
// K3: EUNN recurrence — R6 VERBATIM (measured best: 64.2 us). 2 elems/lane,
// recurrences interleaved by lane parity; exchange = whole-wave rotate-by-2
// via chained DPP wave_rol/ror (pure VALU). modrelu exact reference form.
// ---------------------------------------------------------------------------
__device__ __forceinline__ float rot_up2(float x) {   // lane i <- lane (i+2)%64
    int v = __builtin_amdgcn_mov_dpp(__float_as_int(x), 0x134, 0xF, 0xF, true);
    v = __builtin_amdgcn_mov_dpp(v, 0x134, 0xF, 0xF, true);
    return __int_as_float(v);
}
__device__ __forceinline__ float rot_dn2(float x) {   // lane i <- lane (i-2)%64
    int v = __builtin_amdgcn_mov_dpp(__float_as_int(x), 0x13C, 0xF, 0xF, true);
    v = __builtin_amdgcn_mov_dpp(v, 0x13C, 0xF, 0xF, true);
    return __int_as_float(v);
}

__global__ __launch_bounds__(256) void rnn_kernel(
    const float* __restrict__ attn_f, const float2* __restrict__ u,
    const float* __restrict__ theta, const float* __restrict__ phi,
    const float* __restrict__ rnn_bias, float* __restrict__ rnn_out)
{
    int tid = threadIdx.x;
    int wv = tid >> 6;
    int lane = tid & 63;
    int par = lane & 1;
    int p = lane >> 1;                          // 0..31
    int rec = blockIdx.x * 8 + wv * 2 + par;    // 0..4095
    int qi = rec & 255, h = (rec >> 8) & 7, b = rec >> 11;

    const float* tb = theta + h * 64;
    const float* pb = phi + h * 64;

    float th0 = tb[p], ph0 = pb[p];
    float c0 = cosf(th0), s0 = sinf(th0);
    float cp0 = cosf(ph0), sp0 = sinf(ph0);
    float W0ar = -s0 * cp0, W0ai = -s0 * sp0;
    float W0br =  s0 * cp0, W0bi = -s0 * sp0;

    float th1 = tb[32 + p], ph1 = pb[32 + p];
    float c1 = cosf(th1), s1 = sinf(th1);
    float W1ar = -s1 * cosf(ph1), W1ai = -s1 * sinf(ph1);

    int pm = (p + 31) & 31;
    float th1m = tb[32 + pm], ph1m = pb[32 + pm];
    float c1m = cosf(th1m), s1m = sinf(th1m);
    float W1br = s1m * cosf(ph1m), W1bi = -s1m * sinf(ph1m);

    float bias0 = rnn_bias[h * 64 + 2 * p];
    float bias1 = rnn_bias[h * 64 + 2 * p + 1];

    __shared__ float arow[8 * 256];
    {
        const float4* ap = (const float4*)(attn_f + (size_t)blockIdx.x * 8 * 256);
        ((float4*)arow)[tid] = ap[tid];
        ((float4*)arow)[tid + 256] = ap[tid + 256];
    }
    __syncthreads();
    const float* arc = arow + (wv * 2 + par) * 256;

    const float4* up4 = (const float4*)(u + (size_t)((b * NH + h) * NL) * DQ) + p;

    float e0r = 0.f, e0i = 0.f, e1r = 0.f, e1i = 0.f;
    #pragma unroll 8
    for (int t = 0; t < 256; t++) {
        float4 uu = up4[t * 32];
        float a_t = arc[t];

        float na_r = c0 * e0r + (W0ar * e1r - W0ai * e1i);
        float na_i = c0 * e0i + (W0ar * e1i + W0ai * e1r);
        float nb_r = c0 * e1r + (W0br * e0r - W0bi * e0i);
        float nb_i = c0 * e1i + (W0br * e0i + W0bi * e0r);

        float f1r = rot_up2(na_r), f1i = rot_up2(na_i);
        float f2r = rot_dn2(nb_r), f2i = rot_dn2(nb_i);

        float z1r = c1 * nb_r + (W1ar * f1r - W1ai * f1i);
        float z1i = c1 * nb_i + (W1ar * f1i + W1ai * f1r);
        float z0r = c1m * na_r + (W1br * f2r - W1bi * f2i);
        float z0i = c1m * na_i + (W1br * f2i + W1bi * f2r);

        z0r += a_t * uu.x; z0i += a_t * uu.y;
        z1r += a_t * uu.z; z1i += a_t * uu.w;

        float mm0 = z0r * z0r + z0i * z0i;
        float m0 = __builtin_amdgcn_sqrtf(mm0);
        float sc0 = fmaxf(m0 + bias0, 0.f) * __builtin_amdgcn_rcpf(m0 + 1e-5f);
        e0r = z0r * sc0; e0i = z0i * sc0;

        float mm1 = z1r * z1r + z1i * z1i;
        float m1 = __builtin_amdgcn_sqrtf(mm1);
        float sc1 = fmaxf(m1 + bias1, 0.f) * __builtin_amdgcn_rcpf(m1 + 1e-5f);
        e1r = z1r * sc1; e1i = z1i * sc1;
    }

    float2 o = make_float2(e0r, e1r);
    *(float2*)&rnn_out[(size_t)(b * NL + qi) * DM + h * DQ + 2 * p] = o;
}

// ---------------------------------------------------------------------------
// K4: output projection. 16x64 tile, K-tile 32 (R3 config). grid (8,32).
// ---------------------------------------------------------------------------
__global__ __launch_bounds__(256) void out_gemm(
    const float* __restrict__ A, const float* __restrict__ W,
    const float* __restrict__ bias, float* __restrict__ C)
{
    __shared__ float As[32][17];
    __shared__ float Bs[32][68];

    int tid = threadIdx.x;
    int tx = tid & 15, ty = tid >> 4;
    int m0 = blockIdx.y * 16, n0 = blockIdx.x * 64;

    float acc[4] = {};

    for (int k0 = 0; k0 < 512; k0 += 32) {
        {
            int r = tid >> 4, c2 = (tid & 15) * 2;
            const float2 av = *(const float2*)(A + (m0 + r) * 512 + k0 + c2);
            As[c2 + 0][r] = av.x; As[c2 + 1][r] = av.y;
        }
        {
            int r = tid >> 4, c4 = (tid & 15) * 4;
            float4 b0 = *(const float4*)(W + (k0 + r) * 512 + n0 + c4);
            float4 b1 = *(const float4*)(W + (k0 + r + 16) * 512 + n0 + c4);
            *(float4*)&Bs[r][c4] = b0;
            *(float4*)&Bs[r + 16][c4] = b1;
        }
        __syncthreads();
        #pragma unroll
        for (int kk = 0; kk < 32; kk++) {
            float a = As[kk][ty];
            float4 bb = *(const float4*)&Bs[kk][tx * 4];
            acc[0] += a * bb.x; acc[1] += a * bb.y;
            acc[2] += a * bb.z; acc[3] += a * bb.w;
        }
        __syncthreads();
    }

    int m = m0 + ty;
    #pragma unroll
    for (int j = 0; j < 4; j++) {
        int n = n0 + tx * 4 + j;
        C[m * 512 + n] = acc[j] + bias[n];
    }
}

// ---------------------------------------------------------------------------
extern "C" void kernel_launch(void* const* d_in, const int* in_sizes, int n_in,
                              void* d_out, int out_size, void* d_ws, size_t ws_size,
                              hipStream_t stream)
{
    const float* x_q  = (const float*)d_in[0];
    const float* x_k  = (const float*)d_in[1];
    const float* x_v  = (const float*)d_in[2];
    const float* mask = (const float*)d_in[3];
    const float* Wq   = (const float*)d_in[4];
    const float* bq   = (const float*)d_in[5];
    const float* Wk   = (const float*)d_in[6];
    const float* bk   = (const float*)d_in[7];
    const float* Wv   = (const float*)d_in[8];
    const float* bv   = (const float*)d_in[9];
    const float* Wo   = (const float*)d_in[10];
    const float* bo   = (const float*)d_in[11];
    const float* theta= (const float*)d_in[12];
    const float* phi  = (const float*)d_in[13];
    const float* Wre  = (const float*)d_in[14];
    const float* Wim  = (const float*)d_in[15];
    const float* rb   = (const float*)d_in[16];

    float* ws = (float*)d_ws;
    float*  q_ws    = ws;                       // 262144 f
    float*  kT_ws   = ws + 262144;              // 262144 f (b,h,d,t)
    float*  v_ws    = ws + 524288;              // 262144 f
    float2* u_ws    = (float2*)(ws + 786432);   // 262144 float2
    float*  rnn_o   = ws + 1310720;             // 262144 f

    float* out_o  = (float*)d_out;              // (2,256,512)
    float* attn_o = out_o + NB * NL * DM;       // (2,8,256,256)

    qkv_gemm<<<dim3(8, 16, 3), 256, 0, stream>>>(
        x_q, x_k, x_v, Wq, Wk, Wv, bq, bk, bv, q_ws, kT_ws, v_ws);

    attn_u_kernel<<<dim3(96, NH, NB), 256, 0, stream>>>(
        q_ws, kT_ws, mask, attn_o, v_ws, Wre, Wim, u_ws);

    rnn_kernel<<<dim3(512), 256, 0, stream>>>(
        attn_o, u_ws, theta, phi, rb, rnn_o);

    out_gemm<<<dim3(8, 32), 256, 0, stream>>>(rnn_o, Wo, bo, out_o);
}